// Round 10
// baseline (401.921 us; speedup 1.0000x reference)
//
#include <hip/hip_runtime.h>
#include <hip/hip_fp16.h>

// GraphSAGE 2-layer: logits = meanAgg(relu(meanAgg(x@W1)) @ W2)
// N=100000, E=1600000, D_IN=128, D_H=128, D_OUT=64, fp32 in/out.
//
// R9: MFMA gemms. R10: dwordx4 gathers. R12: wave-uniform shfl.
// R13: flat gather tiers. R14/R17: fp8 agg1 slower (VALU / bpermute cost).
// R15: fp16 + packed v_pk_add_f16 agg: agg1 56us, absmax 0.0039. Proven best.
// R18: build-chain block counts doubled — NEUTRAL (not parallelism-bound).
// R19: counting-sort CSR chain (hist/hscan_row/hscan_base/part/build,
//      ~44MB traffic + serial LDS scans) replaced by direct atomic build:
//      deg atomics (400KB L2-resident counters) -> 3-kernel exclusive scan
//      -> atomic fill. ~28MB traffic, no packed/HT round-trips. csr row
//      order becomes race order (only perturbs fp16 sum order; 3x margin).
//      degc zeroed in k_prep (workspace persists across graph replays).
//      gemm1/agg1/gemm2/agg2 unchanged from R15.

#define DIN 128
#define DH 128
#define DOUT 64

typedef __attribute__((ext_vector_type(8))) short short8;
typedef __attribute__((ext_vector_type(8))) _Float16 half8;
typedef __attribute__((ext_vector_type(4))) float floatx4;

__device__ __forceinline__ unsigned bfpack(float a, float b) {
    unsigned ua = __float_as_uint(a);
    unsigned ub = __float_as_uint(b);
    ua += 0x7fffu + ((ua >> 16) & 1u);
    ub += 0x7fffu + ((ub >> 16) & 1u);
    return (ua >> 16) | (ub & 0xffff0000u);
}
__device__ __forceinline__ unsigned short bf1(float a) {
    unsigned u = __float_as_uint(a);
    u += 0x7fffu + ((u >> 16) & 1u);
    return (unsigned short)(u >> 16);
}

// packed-fp16 accumulate: one uint4 = 8 fp16, 4 v_pk_add_f16
__device__ __forceinline__ void acch2(__half2* a, uint4 v) {
    a[0] = __hadd2(a[0], *(const __half2*)&v.x);
    a[1] = __hadd2(a[1], *(const __half2*)&v.y);
    a[2] = __hadd2(a[2], *(const __half2*)&v.z);
    a[3] = __hadd2(a[3], *(const __half2*)&v.w);
}
__device__ __forceinline__ __half2 h2shfl_xor(__half2 v, int m) {
    int u = __shfl_xor(*(int*)&v, m);
    return *(__half2*)&u;
}
__device__ __forceinline__ unsigned h2bits(__half2 v) {
    return *(unsigned*)&v;
}
__device__ __forceinline__ __half2 h2zero() {
    unsigned z = 0u;
    return *(__half2*)&z;
}

// -------- prep: W transposes + zero degc (grid covers N) --------
__global__ __launch_bounds__(256) void k_prep(const float* __restrict__ W1,
                                              const float* __restrict__ W2,
                                              unsigned short* __restrict__ Wt1,
                                              unsigned short* __restrict__ Wt2,
                                              int* __restrict__ degc, int N) {
    int idx = blockIdx.x * 256 + threadIdx.x;
    if (idx < N) degc[idx] = 0;
    if (idx < 128 * 128) {
        int k = idx >> 7, nn = idx & 127;
        Wt1[nn * 128 + k] = bf1(W1[idx]);          // bf16 for gemm1
    }
    int i2 = idx - 128 * 128;
    if (i2 >= 0 && i2 < 128 * 64) {
        int k = i2 >> 6, nn = i2 & 63;
        Wt2[nn * 128 + k] = __half_as_ushort(__float2half(W2[i2]));  // fp16
    }
}

// -------- CSR build: atomic degree count + scan + atomic fill --------

__global__ __launch_bounds__(256) void k_deg(const int* __restrict__ row,
                                             int* __restrict__ degc, int E) {
    int e = blockIdx.x * 256 + threadIdx.x;
    if (e < E) atomicAdd(&degc[row[e]], 1);
}

// block-local exclusive scan of degc (1024/block); bsum[b] = block total
__global__ __launch_bounds__(1024) void k_scan1(const int* __restrict__ degc,
                                                int* __restrict__ offs,
                                                int* __restrict__ bsum, int N) {
    __shared__ int sh[1024];
    int t = threadIdx.x;
    int base = blockIdx.x * 1024;
    int v = (base + t < N) ? degc[base + t] : 0;
    sh[t] = v;
    __syncthreads();
    for (int d = 1; d < 1024; d <<= 1) {
        int u = (t >= d) ? sh[t - d] : 0;
        __syncthreads();
        sh[t] += u;
        __syncthreads();
    }
    if (base + t < N) offs[base + t] = sh[t] - v;   // local exclusive
    if (t == 1023) bsum[blockIdx.x] = sh[1023];
}

// exclusive scan of the (<=128) block totals, in place
__global__ __launch_bounds__(128) void k_scan2(int* __restrict__ bsum, int nsb) {
    __shared__ int sh[128];
    int t = threadIdx.x;
    int v = (t < nsb) ? bsum[t] : 0;
    sh[t] = v;
    __syncthreads();
    for (int d = 1; d < 128; d <<= 1) {
        int u = (t >= d) ? sh[t - d] : 0;
        __syncthreads();
        sh[t] += u;
        __syncthreads();
    }
    if (t < nsb) bsum[t] = sh[t] - v;               // exclusive base
}

// finalize: offs += base; cur = offs; invdeg = 1/deg
__global__ __launch_bounds__(256) void k_scan3(int* __restrict__ offs,
                                               const int* __restrict__ bsum,
                                               const int* __restrict__ degc,
                                               int* __restrict__ cur,
                                               float* __restrict__ invdeg, int N) {
    int i = blockIdx.x * 256 + threadIdx.x;
    if (i < N) {
        int o = offs[i] + bsum[i >> 10];
        offs[i] = o;
        cur[i] = o;
        invdeg[i] = 1.0f / (float)degc[i];
    }
}

__global__ __launch_bounds__(256) void k_fill(const int* __restrict__ row,
                                              const int* __restrict__ col,
                                              int* __restrict__ cur,
                                              int* __restrict__ csr, int E) {
    int e = blockIdx.x * 256 + threadIdx.x;
    if (e < E) {
        int pos = atomicAdd(&cur[row[e]], 1);
        csr[pos] = col[e];
    }
}

// ---------------- MFMA GEMMs ----------------

// h1h[n,128](fp16) = X @ W1 (bf16 MFMA, fp16 store). 64-row block.
__global__ __launch_bounds__(256) void k_gemm1(const float* __restrict__ X,
                                               const unsigned short* __restrict__ Wt,
                                               unsigned short* __restrict__ H1h, int n) {
    __shared__ unsigned short xs[64][136];    // pitch 272B: 2-way-bank-safe b128
    __shared__ unsigned short wt[128][136];
    int tid = threadIdx.x;
    int r0 = blockIdx.x * 64;

    for (int i = tid; i < 64 * 32; i += 256) {
        int r = i >> 5, c4 = i & 31;
        float4 v = make_float4(0.f, 0.f, 0.f, 0.f);
        if (r0 + r < n) v = ((const float4*)X)[(size_t)(r0 + r) * 32 + c4];
        *(uint2*)&xs[r][c4 * 4] = make_uint2(bfpack(v.x, v.y), bfpack(v.z, v.w));
    }
    for (int i = tid; i < 128 * 16; i += 256) {
        int r = i >> 4, c = i & 15;
        *(uint4*)&wt[r][c * 8] = ((const uint4*)Wt)[r * 16 + c];
    }
    __syncthreads();

    int w = tid >> 6, lane = tid & 63;
    int ml = lane & 15, q = lane >> 4;
    floatx4 acc[8];
#pragma unroll
    for (int t = 0; t < 8; ++t) acc[t] = (floatx4)(0.f);

#pragma unroll
    for (int kc = 0; kc < 4; ++kc) {
        short8 af = *(const short8*)&xs[w * 16 + ml][kc * 32 + q * 8];
#pragma unroll
        for (int nt = 0; nt < 8; ++nt) {
            short8 bf = *(const short8*)&wt[nt * 16 + ml][kc * 32 + q * 8];
            acc[nt] = __builtin_amdgcn_mfma_f32_16x16x32_bf16(af, bf, acc[nt], 0, 0, 0);
        }
    }
#pragma unroll
    for (int nt = 0; nt < 8; ++nt)
#pragma unroll
        for (int r = 0; r < 4; ++r) {
            int rr = r0 + w * 16 + q * 4 + r;
            if (rr < n)
                H1h[(size_t)rr * 128 + nt * 16 + ml] =
                    __half_as_ushort(__float2half(acc[nt][r]));
        }
}

// h2h[n,64](fp16) = h(fp16) @ W2 (f16 MFMA). Same structure, N=64.
__global__ __launch_bounds__(256) void k_gemm2(const unsigned* __restrict__ Hin,
                                               const unsigned short* __restrict__ Wt,
                                               unsigned short* __restrict__ H2h, int n) {
    __shared__ unsigned short xs[64][136];
    __shared__ unsigned short wt[64][136];
    int tid = threadIdx.x;
    int r0 = blockIdx.x * 64;

    for (int i = tid; i < 64 * 16; i += 256) {
        int r = i >> 4, c = i & 15;
        uint4 v = make_uint4(0u, 0u, 0u, 0u);
        if (r0 + r < n) v = ((const uint4*)Hin)[(size_t)(r0 + r) * 16 + c];
        *(uint4*)&xs[r][c * 8] = v;
    }
    for (int i = tid; i < 64 * 16; i += 256) {
        int r = i >> 4, c = i & 15;
        *(uint4*)&wt[r][c * 8] = ((const uint4*)Wt)[r * 16 + c];
    }
    __syncthreads();

    int w = tid >> 6, lane = tid & 63;
    int ml = lane & 15, q = lane >> 4;
    floatx4 acc[4];
#pragma unroll
    for (int t = 0; t < 4; ++t) acc[t] = (floatx4)(0.f);

#pragma unroll
    for (int kc = 0; kc < 4; ++kc) {
        half8 af = *(const half8*)&xs[w * 16 + ml][kc * 32 + q * 8];
#pragma unroll
        for (int nt = 0; nt < 4; ++nt) {
            half8 bf = *(const half8*)&wt[nt * 16 + ml][kc * 32 + q * 8];
            acc[nt] = __builtin_amdgcn_mfma_f32_16x16x32_f16(af, bf, acc[nt], 0, 0, 0);
        }
    }
#pragma unroll
    for (int nt = 0; nt < 4; ++nt)
#pragma unroll
        for (int r = 0; r < 4; ++r) {
            int rr = r0 + w * 16 + q * 4 + r;
            if (rr < n)
                H2h[(size_t)rr * 64 + nt * 16 + ml] =
                    __half_as_ushort(__float2half(acc[nt][r]));
        }
}

// ---------------- Aggregations (R15 structure, unchanged) ----------------

// agg1: h[row](fp16) = relu((1/deg) * sum h1h[c]), D=128 (row = 16 uint4).
#define A1_SLOT(vv, s)                                                      \
    {                                                                       \
        int j = (s) * 4 + g;                                                \
        int c = __shfl(idx, (j < nd) ? j : 0);                              \
        vv = make_uint4(0u, 0u, 0u, 0u);                                    \
        if (j < nd) vv = H1h[((unsigned)c << 4) + sl];                      \
    }

__global__ __launch_bounds__(256) void k_agg1(const uint4* __restrict__ H1h,
                                              const int* __restrict__ offs,
                                              const int* __restrict__ degc,
                                              const float* __restrict__ invdeg,
                                              const int* __restrict__ csr,
                                              uint4* __restrict__ Hout, int n) {
    int wave = threadIdx.x >> 6, lane = threadIdx.x & 63;
    int row = blockIdx.x * 4 + wave;
    if (row >= n) return;
    int start = offs[row], d = degc[row];
    float inv = invdeg[row];
    int g = lane >> 4;       // neighbor slot 0..3
    int sl = lane & 15;      // 16B segment within 256B fp16 row

    int nd = d < 64 ? d : 64;
    int idx = (lane < nd) ? csr[start + lane] : 0;

    __half2 acc[4];
#pragma unroll
    for (int k = 0; k < 4; ++k) acc[k] = h2zero();

    uint4 v0, v1, v2, v3;
    A1_SLOT(v0, 0) A1_SLOT(v1, 1) A1_SLOT(v2, 2) A1_SLOT(v3, 3)
    acch2(acc, v0); acch2(acc, v1); acch2(acc, v2); acch2(acc, v3);
    if (nd > 16) {
        A1_SLOT(v0, 4) A1_SLOT(v1, 5) A1_SLOT(v2, 6) A1_SLOT(v3, 7)
        acch2(acc, v0); acch2(acc, v1); acch2(acc, v2); acch2(acc, v3);
    }
    if (nd > 32) {
        A1_SLOT(v0, 8) A1_SLOT(v1, 9) A1_SLOT(v2, 10) A1_SLOT(v3, 11)
        acch2(acc, v0); acch2(acc, v1); acch2(acc, v2); acch2(acc, v3);
    }
    if (nd > 48) {
        A1_SLOT(v0, 12) A1_SLOT(v1, 13) A1_SLOT(v2, 14) A1_SLOT(v3, 15)
        acch2(acc, v0); acch2(acc, v1); acch2(acc, v2); acch2(acc, v3);
    }
    if (d > 64) {                    // rare fallback
        for (int i = 64; i < d; i += 4) {
            int j = i + g;
            uint4 v = make_uint4(0u, 0u, 0u, 0u);
            if (j < d) {
                int c = csr[start + j];
                v = H1h[((unsigned)c << 4) + sl];
            }
            acch2(acc, v);
        }
    }

#pragma unroll
    for (int k = 0; k < 4; ++k) {
        acc[k] = __hadd2(acc[k], h2shfl_xor(acc[k], 16));
        acc[k] = __hadd2(acc[k], h2shfl_xor(acc[k], 32));
    }

    if (g == 0) {
        float f[8];
#pragma unroll
        for (int k = 0; k < 4; ++k) {
            f[2 * k]     = fmaxf(__low2float(acc[k]) * inv, 0.f);
            f[2 * k + 1] = fmaxf(__high2float(acc[k]) * inv, 0.f);
        }
        uint4 o;
        __half2 t0 = __floats2half2_rn(f[0], f[1]);
        __half2 t1 = __floats2half2_rn(f[2], f[3]);
        __half2 t2 = __floats2half2_rn(f[4], f[5]);
        __half2 t3 = __floats2half2_rn(f[6], f[7]);
        o.x = h2bits(t0); o.y = h2bits(t1); o.z = h2bits(t2); o.w = h2bits(t3);
        Hout[(size_t)row * 16 + sl] = o;
    }
}

// agg2: Out[row](fp32) = (1/deg) * sum h2h[c], D=64 (row = 8 uint4, fp16).
#define A2_SLOT(vv, s)                                                      \
    {                                                                       \
        int j = (s) * 8 + g;                                                \
        int c = __shfl(idx, (j < nd) ? j : 0);                              \
        vv = make_uint4(0u, 0u, 0u, 0u);                                    \
        if (j < nd) vv = H2h[((unsigned)c << 3) + sl];                      \
    }

__global__ __launch_bounds__(256) void k_agg2(const uint4* __restrict__ H2h,
                                              const int* __restrict__ offs,
                                              const int* __restrict__ degc,
                                              const float* __restrict__ invdeg,
                                              const int* __restrict__ csr,
                                              float* __restrict__ Out, int n) {
    int wave = threadIdx.x >> 6, lane = threadIdx.x & 63;
    int row = blockIdx.x * 4 + wave;
    if (row >= n) return;
    int start = offs[row], d = degc[row];
    float inv = invdeg[row];
    int g = lane >> 3;       // neighbor slot 0..7
    int sl = lane & 7;       // 16B segment within 128B fp16 row

    int nd = d < 64 ? d : 64;
    int idx = (lane < nd) ? csr[start + lane] : 0;

    __half2 acc[4];
#pragma unroll
    for (int k = 0; k < 4; ++k) acc[k] = h2zero();

    uint4 v0, v1;
    A2_SLOT(v0, 0) A2_SLOT(v1, 1)
    acch2(acc, v0); acch2(acc, v1);
    if (nd > 16) {
        A2_SLOT(v0, 2) A2_SLOT(v1, 3)
        acch2(acc, v0); acch2(acc, v1);
    }
    if (nd > 32) {
        A2_SLOT(v0, 4) A2_SLOT(v1, 5)
        acch2(acc, v0); acch2(acc, v1);
    }
    if (nd > 48) {
        A2_SLOT(v0, 6) A2_SLOT(v1, 7)
        acch2(acc, v0); acch2(acc, v1);
    }
    if (d > 64) {                    // rare fallback
        for (int i = 64; i < d; i += 8) {
            int j = i + g;
            uint4 v = make_uint4(0u, 0u, 0u, 0u);
            if (j < d) {
                int c = csr[start + j];
                v = H2h[((unsigned)c << 3) + sl];
            }
            acch2(acc, v);
        }
    }

#pragma unroll
    for (int k = 0; k < 4; ++k) {
        acc[k] = __hadd2(acc[k], h2shfl_xor(acc[k], 8));
        acc[k] = __hadd2(acc[k], h2shfl_xor(acc[k], 16));
        acc[k] = __hadd2(acc[k], h2shfl_xor(acc[k], 32));
    }

    if (g == 0) {
        float4 o0, o1;
        o0.x = __low2float(acc[0]) * inv;  o0.y = __high2float(acc[0]) * inv;
        o0.z = __low2float(acc[1]) * inv;  o0.w = __high2float(acc[1]) * inv;
        o1.x = __low2float(acc[2]) * inv;  o1.y = __high2float(acc[2]) * inv;
        o1.z = __low2float(acc[3]) * inv;  o1.w = __high2float(acc[3]) * inv;
        ((float4*)Out)[(size_t)row * 16 + sl * 2]     = o0;
        ((float4*)Out)[(size_t)row * 16 + sl * 2 + 1] = o1;
    }
}

extern "C" void kernel_launch(void* const* d_in, const int* in_sizes, int n_in,
                              void* d_out, int out_size, void* d_ws, size_t ws_size,
                              hipStream_t stream) {
    const float* x    = (const float*)d_in[0];
    const float* W1   = (const float*)d_in[1];
    const float* W2   = (const float*)d_in[2];
    const int*   erow = (const int*)d_in[3];
    const int*   ecol = (const int*)d_in[4];
    const int N = in_sizes[0] / DIN;
    const int E = in_sizes[3];

    const int nsb = (N + 1023) >> 10;      // scan1 blocks (98)

    size_t o = 0;
    auto take = [&](size_t nbytes) {
        void* p = (char*)d_ws + o;
        o += (nbytes + 255) & ~(size_t)255;
        return p;
    };
    int*            csr    = (int*)take((size_t)E * 4);
    int*            offs   = (int*)take((size_t)N * 4);
    int*            degc   = (int*)take((size_t)N * 4);
    int*            cur    = (int*)take((size_t)N * 4);
    int*            bsum   = (int*)take((size_t)(nsb + 1) * 4);
    float*          invdeg = (float*)take((size_t)N * 4);
    unsigned short* Wt1    = (unsigned short*)take(128 * 128 * 2);
    unsigned short* Wt2    = (unsigned short*)take(64 * 128 * 2);
    unsigned short* h1h    = (unsigned short*)take((size_t)N * DH * 2);  // fp16
    unsigned*       h      = (unsigned*)take((size_t)N * DH * 2);        // fp16
    unsigned short* h2h    = h1h;   // reuse (dead after agg1); 12.8MB needed

    k_prep <<<(N + 255) / 256, 256, 0, stream>>>(W1, W2, Wt1, Wt2, degc, N);
    k_deg  <<<(E + 255) / 256, 256, 0, stream>>>(erow, degc, E);
    k_scan1<<<nsb, 1024, 0, stream>>>(degc, offs, bsum, N);
    k_scan2<<<1, 128, 0, stream>>>(bsum, nsb);
    k_scan3<<<(N + 255) / 256, 256, 0, stream>>>(offs, bsum, degc, cur, invdeg, N);
    k_fill <<<(E + 255) / 256, 256, 0, stream>>>(erow, ecol, cur, csr, E);
    k_gemm1<<<(N + 63) / 64, 256, 0, stream>>>(x, Wt1, h1h, N);
    k_agg1 <<<(N + 3) / 4, 256, 0, stream>>>((const uint4*)h1h, offs, degc, invdeg,
                                             csr, (uint4*)h, N);
    k_gemm2<<<(N + 63) / 64, 256, 0, stream>>>(h, Wt2, h2h, N);
    k_agg2 <<<(N + 3) / 4, 256, 0, stream>>>((const uint4*)h2h, offs, degc,
                                             invdeg, csr, (float*)d_out, N);
}

// Round 11
// 268.822 us; speedup vs baseline: 1.4951x; 1.4951x over previous
//
#include <hip/hip_runtime.h>
#include <hip/hip_fp16.h>

// GraphSAGE 2-layer: logits = meanAgg(relu(meanAgg(x@W1)) @ W2)
// N=100000, E=1600000, D_IN=128, D_H=128, D_OUT=64, fp32 in/out.
//
// R9: MFMA gemms. R10: dwordx4 gathers. R12: wave-uniform shfl.
// R13: flat gather tiers. R14/R17: fp8 agg1 slower (VALU / bpermute cost).
// R15: fp16 + packed v_pk_add_f16 agg: agg1 56us, absmax 0.0039. Proven best.
// R18: build-chain block counts doubled — neutral. 265.1us. BEST.
// R19: FAILED: atomic CSR fill scattered 4B csr writes in race order across
//      8 non-coherent XCD L2s -> partial-line writebacks, WRITE_SIZE 103MB
//      (16x amplification), k_fill 120us. Counting sort exists to give each
//      block a contiguous single-writer csr region.
// R20: revert to R18 exactly (best verified). All components independently
//      validated as local optima; agg1/agg2 pinned at the random-gather
//      L2-miss path ceiling (~3.7 TB/s, invariant across 4 attacks).

#define DIN 128
#define DH 128
#define DOUT 64

#define BSH 8                    // 256 rows per bucket
#define COLB 17                  // col fits 17 bits (N=100000 < 2^17)
#define COLM ((1 << COLB) - 1)
#define LRM ((1 << BSH) - 1)
#define CHUNK 2048               // edges per hist/part block
#define CH_PT 8                  // edges per thread

typedef __attribute__((ext_vector_type(8))) short short8;
typedef __attribute__((ext_vector_type(8))) _Float16 half8;
typedef __attribute__((ext_vector_type(4))) float floatx4;

__device__ __forceinline__ unsigned bfpack(float a, float b) {
    unsigned ua = __float_as_uint(a);
    unsigned ub = __float_as_uint(b);
    ua += 0x7fffu + ((ua >> 16) & 1u);
    ub += 0x7fffu + ((ub >> 16) & 1u);
    return (ua >> 16) | (ub & 0xffff0000u);
}
__device__ __forceinline__ unsigned short bf1(float a) {
    unsigned u = __float_as_uint(a);
    u += 0x7fffu + ((u >> 16) & 1u);
    return (unsigned short)(u >> 16);
}

// packed-fp16 accumulate: one uint4 = 8 fp16, 4 v_pk_add_f16
__device__ __forceinline__ void acch2(__half2* a, uint4 v) {
    a[0] = __hadd2(a[0], *(const __half2*)&v.x);
    a[1] = __hadd2(a[1], *(const __half2*)&v.y);
    a[2] = __hadd2(a[2], *(const __half2*)&v.z);
    a[3] = __hadd2(a[3], *(const __half2*)&v.w);
}
__device__ __forceinline__ __half2 h2shfl_xor(__half2 v, int m) {
    int u = __shfl_xor(*(int*)&v, m);
    return *(__half2*)&u;
}
__device__ __forceinline__ unsigned h2bits(__half2 v) {
    return *(unsigned*)&v;
}
__device__ __forceinline__ __half2 h2zero() {
    unsigned z = 0u;
    return *(__half2*)&z;
}

// ---------------- weight prep: fp32 [k][n] -> bf16/fp16 [n][k] ----------
__global__ __launch_bounds__(256) void k_prep(const float* __restrict__ W1,
                                              const float* __restrict__ W2,
                                              unsigned short* __restrict__ Wt1,
                                              unsigned short* __restrict__ Wt2) {
    int idx = blockIdx.x * 256 + threadIdx.x;
    if (idx < 128 * 128) {
        int k = idx >> 7, nn = idx & 127;
        Wt1[nn * 128 + k] = bf1(W1[idx]);          // bf16 for gemm1
    }
    int i2 = idx - 128 * 128;
    if (i2 >= 0 && i2 < 128 * 64) {
        int k = i2 >> 6, nn = i2 & 63;
        Wt2[nn * 128 + k] = __half_as_ushort(__float2half(W2[i2]));  // fp16
    }
}

// ---------------- CSR build (counting sort) ----------------

__global__ __launch_bounds__(256) void k_hist(const int* __restrict__ row,
                                              int* __restrict__ HT,
                                              int E, int nb, int nch) {
    __shared__ int h[512];
    int t = threadIdx.x, c = blockIdx.x;
    for (int i = t; i < nb; i += 256) h[i] = 0;
    __syncthreads();
    int base = c * CHUNK;
#pragma unroll
    for (int i = 0; i < CH_PT; ++i) {
        int e = base + i * 256 + t;
        if (e < E) atomicAdd(&h[row[e] >> BSH], 1);
    }
    __syncthreads();
    for (int i = t; i < nb; i += 256) HT[(size_t)i * nch + c] = h[i];
}

__global__ __launch_bounds__(256) void k_hscan_row(int* __restrict__ HT,
                                                   int* __restrict__ bsum,
                                                   int nch) {
    __shared__ int sh[256];
    int b = blockIdx.x, t = threadIdx.x;
    int carry = 0;
    for (int tile = 0; tile < nch; tile += 256) {
        int idx = tile + t;
        int v = (idx < nch) ? HT[(size_t)b * nch + idx] : 0;
        sh[t] = v;
        __syncthreads();
        for (int d = 1; d < 256; d <<= 1) {
            int u = (t >= d) ? sh[t - d] : 0;
            __syncthreads();
            sh[t] += u;
            __syncthreads();
        }
        if (idx < nch) HT[(size_t)b * nch + idx] = carry + sh[t] - v;
        carry += sh[255];
        __syncthreads();
    }
    if (t == 0) bsum[b] = carry;
}

// 512-thread scan (nb up to 512 buckets with BSH=8)
__global__ __launch_bounds__(512) void k_hscan_base(const int* __restrict__ bsum,
                                                    int* __restrict__ bucketBase,
                                                    int nb, int E) {
    __shared__ int sh[512];
    int t = threadIdx.x;
    int v = (t < nb) ? bsum[t] : 0;
    sh[t] = v;
    __syncthreads();
    for (int d = 1; d < 512; d <<= 1) {
        int u = (t >= d) ? sh[t - d] : 0;
        __syncthreads();
        sh[t] += u;
        __syncthreads();
    }
    if (t < nb) bucketBase[t] = sh[t] - v;
    if (t == 0) bucketBase[nb] = E;
}

__global__ __launch_bounds__(256) void k_part(const int* __restrict__ row,
                                              const int* __restrict__ col,
                                              const int* __restrict__ HT,
                                              const int* __restrict__ bucketBase,
                                              int* __restrict__ packed,
                                              int E, int nb, int nch) {
    __shared__ int cur[512];
    int t = threadIdx.x, c = blockIdx.x;
    for (int i = t; i < nb; i += 256)
        cur[i] = HT[(size_t)i * nch + c] + bucketBase[i];
    __syncthreads();
    int base = c * CHUNK;
#pragma unroll
    for (int i = 0; i < CH_PT; ++i) {
        int e = base + i * 256 + t;
        if (e < E) {
            int r = row[e], cc = col[e];
            int b = r >> BSH;
            int pos = atomicAdd(&cur[b], 1);
            packed[pos] = ((r & LRM) << COLB) | cc;
        }
    }
}

__global__ __launch_bounds__(256) void k_build(const int* __restrict__ packed,
                                               const int* __restrict__ bucketBase,
                                               int* __restrict__ csr,
                                               int* __restrict__ offs,
                                               int* __restrict__ degc,
                                               float* __restrict__ invdeg,
                                               int N, int nb) {
    __shared__ int hist[256], scn[256], part[256];
    int t = threadIdx.x, b = blockIdx.x;
    int lo = bucketBase[b], hi = bucketBase[b + 1];
    int base_row = b << BSH;
    int nloc = N - base_row; if (nloc > 256) nloc = 256;
    hist[t] = 0;
    __syncthreads();
    for (int e = lo + t; e < hi; e += 256)
        atomicAdd(&hist[packed[e] >> COLB], 1);
    __syncthreads();
    int a = hist[t];
    part[t] = a;
    __syncthreads();
    for (int d = 1; d < 256; d <<= 1) {
        int v = (t >= d) ? part[t - d] : 0;
        __syncthreads();
        part[t] += v;
        __syncthreads();
    }
    scn[t] = part[t] - a;              // exclusive scan
    __syncthreads();
    for (int i = t; i < nloc; i += 256) {
        int r = base_row + i;
        offs[r] = lo + scn[i];
        int d = hist[i];
        degc[r] = d;
        invdeg[r] = 1.0f / (float)d;
    }
    __syncthreads();
    for (int e = lo + t; e < hi; e += 256) {
        int p = packed[e];
        int pos = lo + atomicAdd(&scn[p >> COLB], 1);
        csr[pos] = p & COLM;
    }
}

// ---------------- MFMA GEMMs ----------------

// h1h[n,128](fp16) = X @ W1 (bf16 MFMA, fp16 store). 64-row block.
__global__ __launch_bounds__(256) void k_gemm1(const float* __restrict__ X,
                                               const unsigned short* __restrict__ Wt,
                                               unsigned short* __restrict__ H1h, int n) {
    __shared__ unsigned short xs[64][136];    // pitch 272B: 2-way-bank-safe b128
    __shared__ unsigned short wt[128][136];
    int tid = threadIdx.x;
    int r0 = blockIdx.x * 64;

    for (int i = tid; i < 64 * 32; i += 256) {
        int r = i >> 5, c4 = i & 31;
        float4 v = make_float4(0.f, 0.f, 0.f, 0.f);
        if (r0 + r < n) v = ((const float4*)X)[(size_t)(r0 + r) * 32 + c4];
        *(uint2*)&xs[r][c4 * 4] = make_uint2(bfpack(v.x, v.y), bfpack(v.z, v.w));
    }
    for (int i = tid; i < 128 * 16; i += 256) {
        int r = i >> 4, c = i & 15;
        *(uint4*)&wt[r][c * 8] = ((const uint4*)Wt)[r * 16 + c];
    }
    __syncthreads();

    int w = tid >> 6, lane = tid & 63;
    int ml = lane & 15, q = lane >> 4;
    floatx4 acc[8];
#pragma unroll
    for (int t = 0; t < 8; ++t) acc[t] = (floatx4)(0.f);

#pragma unroll
    for (int kc = 0; kc < 4; ++kc) {
        short8 af = *(const short8*)&xs[w * 16 + ml][kc * 32 + q * 8];
#pragma unroll
        for (int nt = 0; nt < 8; ++nt) {
            short8 bf = *(const short8*)&wt[nt * 16 + ml][kc * 32 + q * 8];
            acc[nt] = __builtin_amdgcn_mfma_f32_16x16x32_bf16(af, bf, acc[nt], 0, 0, 0);
        }
    }
#pragma unroll
    for (int nt = 0; nt < 8; ++nt)
#pragma unroll
        for (int r = 0; r < 4; ++r) {
            int rr = r0 + w * 16 + q * 4 + r;
            if (rr < n)
                H1h[(size_t)rr * 128 + nt * 16 + ml] =
                    __half_as_ushort(__float2half(acc[nt][r]));
        }
}

// h2h[n,64](fp16) = h(fp16) @ W2 (f16 MFMA). Same structure, N=64.
__global__ __launch_bounds__(256) void k_gemm2(const unsigned* __restrict__ Hin,
                                               const unsigned short* __restrict__ Wt,
                                               unsigned short* __restrict__ H2h, int n) {
    __shared__ unsigned short xs[64][136];
    __shared__ unsigned short wt[64][136];
    int tid = threadIdx.x;
    int r0 = blockIdx.x * 64;

    for (int i = tid; i < 64 * 16; i += 256) {
        int r = i >> 4, c = i & 15;
        uint4 v = make_uint4(0u, 0u, 0u, 0u);
        if (r0 + r < n) v = ((const uint4*)Hin)[(size_t)(r0 + r) * 16 + c];
        *(uint4*)&xs[r][c * 8] = v;
    }
    for (int i = tid; i < 64 * 16; i += 256) {
        int r = i >> 4, c = i & 15;
        *(uint4*)&wt[r][c * 8] = ((const uint4*)Wt)[r * 16 + c];
    }
    __syncthreads();

    int w = tid >> 6, lane = tid & 63;
    int ml = lane & 15, q = lane >> 4;
    floatx4 acc[4];
#pragma unroll
    for (int t = 0; t < 4; ++t) acc[t] = (floatx4)(0.f);

#pragma unroll
    for (int kc = 0; kc < 4; ++kc) {
        half8 af = *(const half8*)&xs[w * 16 + ml][kc * 32 + q * 8];
#pragma unroll
        for (int nt = 0; nt < 4; ++nt) {
            half8 bf = *(const half8*)&wt[nt * 16 + ml][kc * 32 + q * 8];
            acc[nt] = __builtin_amdgcn_mfma_f32_16x16x32_f16(af, bf, acc[nt], 0, 0, 0);
        }
    }
#pragma unroll
    for (int nt = 0; nt < 4; ++nt)
#pragma unroll
        for (int r = 0; r < 4; ++r) {
            int rr = r0 + w * 16 + q * 4 + r;
            if (rr < n)
                H2h[(size_t)rr * 64 + nt * 16 + ml] =
                    __half_as_ushort(__float2half(acc[nt][r]));
        }
}

// ---------------- Aggregations (R15 structure) ----------------

// agg1: h[row](fp16) = relu((1/deg) * sum h1h[c]), D=128 (row = 16 uint4).
#define A1_SLOT(vv, s)                                                      \
    {                                                                       \
        int j = (s) * 4 + g;                                                \
        int c = __shfl(idx, (j < nd) ? j : 0);                              \
        vv = make_uint4(0u, 0u, 0u, 0u);                                    \
        if (j < nd) vv = H1h[((unsigned)c << 4) + sl];                      \
    }

__global__ __launch_bounds__(256) void k_agg1(const uint4* __restrict__ H1h,
                                              const int* __restrict__ offs,
                                              const int* __restrict__ degc,
                                              const float* __restrict__ invdeg,
                                              const int* __restrict__ csr,
                                              uint4* __restrict__ Hout, int n) {
    int wave = threadIdx.x >> 6, lane = threadIdx.x & 63;
    int row = blockIdx.x * 4 + wave;
    if (row >= n) return;
    int start = offs[row], d = degc[row];
    float inv = invdeg[row];
    int g = lane >> 4;       // neighbor slot 0..3
    int sl = lane & 15;      // 16B segment within 256B fp16 row

    int nd = d < 64 ? d : 64;
    int idx = (lane < nd) ? csr[start + lane] : 0;

    __half2 acc[4];
#pragma unroll
    for (int k = 0; k < 4; ++k) acc[k] = h2zero();

    uint4 v0, v1, v2, v3;
    A1_SLOT(v0, 0) A1_SLOT(v1, 1) A1_SLOT(v2, 2) A1_SLOT(v3, 3)
    acch2(acc, v0); acch2(acc, v1); acch2(acc, v2); acch2(acc, v3);
    if (nd > 16) {
        A1_SLOT(v0, 4) A1_SLOT(v1, 5) A1_SLOT(v2, 6) A1_SLOT(v3, 7)
        acch2(acc, v0); acch2(acc, v1); acch2(acc, v2); acch2(acc, v3);
    }
    if (nd > 32) {
        A1_SLOT(v0, 8) A1_SLOT(v1, 9) A1_SLOT(v2, 10) A1_SLOT(v3, 11)
        acch2(acc, v0); acch2(acc, v1); acch2(acc, v2); acch2(acc, v3);
    }
    if (nd > 48) {
        A1_SLOT(v0, 12) A1_SLOT(v1, 13) A1_SLOT(v2, 14) A1_SLOT(v3, 15)
        acch2(acc, v0); acch2(acc, v1); acch2(acc, v2); acch2(acc, v3);
    }
    if (d > 64) {                    // rare fallback
        for (int i = 64; i < d; i += 4) {
            int j = i + g;
            uint4 v = make_uint4(0u, 0u, 0u, 0u);
            if (j < d) {
                int c = csr[start + j];
                v = H1h[((unsigned)c << 4) + sl];
            }
            acch2(acc, v);
        }
    }

#pragma unroll
    for (int k = 0; k < 4; ++k) {
        acc[k] = __hadd2(acc[k], h2shfl_xor(acc[k], 16));
        acc[k] = __hadd2(acc[k], h2shfl_xor(acc[k], 32));
    }

    if (g == 0) {
        float f[8];
#pragma unroll
        for (int k = 0; k < 4; ++k) {
            f[2 * k]     = fmaxf(__low2float(acc[k]) * inv, 0.f);
            f[2 * k + 1] = fmaxf(__high2float(acc[k]) * inv, 0.f);
        }
        uint4 o;
        __half2 t0 = __floats2half2_rn(f[0], f[1]);
        __half2 t1 = __floats2half2_rn(f[2], f[3]);
        __half2 t2 = __floats2half2_rn(f[4], f[5]);
        __half2 t3 = __floats2half2_rn(f[6], f[7]);
        o.x = h2bits(t0); o.y = h2bits(t1); o.z = h2bits(t2); o.w = h2bits(t3);
        Hout[(size_t)row * 16 + sl] = o;
    }
}

// agg2: Out[row](fp32) = (1/deg) * sum h2h[c], D=64 (row = 8 uint4, fp16).
#define A2_SLOT(vv, s)                                                      \
    {                                                                       \
        int j = (s) * 8 + g;                                                \
        int c = __shfl(idx, (j < nd) ? j : 0);                              \
        vv = make_uint4(0u, 0u, 0u, 0u);                                    \
        if (j < nd) vv = H2h[((unsigned)c << 3) + sl];                      \
    }

__global__ __launch_bounds__(256) void k_agg2(const uint4* __restrict__ H2h,
                                              const int* __restrict__ offs,
                                              const int* __restrict__ degc,
                                              const float* __restrict__ invdeg,
                                              const int* __restrict__ csr,
                                              float* __restrict__ Out, int n) {
    int wave = threadIdx.x >> 6, lane = threadIdx.x & 63;
    int row = blockIdx.x * 4 + wave;
    if (row >= n) return;
    int start = offs[row], d = degc[row];
    float inv = invdeg[row];
    int g = lane >> 3;       // neighbor slot 0..7
    int sl = lane & 7;       // 16B segment within 128B fp16 row

    int nd = d < 64 ? d : 64;
    int idx = (lane < nd) ? csr[start + lane] : 0;

    __half2 acc[4];
#pragma unroll
    for (int k = 0; k < 4; ++k) acc[k] = h2zero();

    uint4 v0, v1;
    A2_SLOT(v0, 0) A2_SLOT(v1, 1)
    acch2(acc, v0); acch2(acc, v1);
    if (nd > 16) {
        A2_SLOT(v0, 2) A2_SLOT(v1, 3)
        acch2(acc, v0); acch2(acc, v1);
    }
    if (nd > 32) {
        A2_SLOT(v0, 4) A2_SLOT(v1, 5)
        acch2(acc, v0); acch2(acc, v1);
    }
    if (nd > 48) {
        A2_SLOT(v0, 6) A2_SLOT(v1, 7)
        acch2(acc, v0); acch2(acc, v1);
    }
    if (d > 64) {                    // rare fallback
        for (int i = 64; i < d; i += 8) {
            int j = i + g;
            uint4 v = make_uint4(0u, 0u, 0u, 0u);
            if (j < d) {
                int c = csr[start + j];
                v = H2h[((unsigned)c << 3) + sl];
            }
            acch2(acc, v);
        }
    }

#pragma unroll
    for (int k = 0; k < 4; ++k) {
        acc[k] = __hadd2(acc[k], h2shfl_xor(acc[k], 8));
        acc[k] = __hadd2(acc[k], h2shfl_xor(acc[k], 16));
        acc[k] = __hadd2(acc[k], h2shfl_xor(acc[k], 32));
    }

    if (g == 0) {
        float4 o0, o1;
        o0.x = __low2float(acc[0]) * inv;  o0.y = __high2float(acc[0]) * inv;
        o0.z = __low2float(acc[1]) * inv;  o0.w = __high2float(acc[1]) * inv;
        o1.x = __low2float(acc[2]) * inv;  o1.y = __high2float(acc[2]) * inv;
        o1.z = __low2float(acc[3]) * inv;  o1.w = __high2float(acc[3]) * inv;
        ((float4*)Out)[(size_t)row * 16 + sl * 2]     = o0;
        ((float4*)Out)[(size_t)row * 16 + sl * 2 + 1] = o1;
    }
}

extern "C" void kernel_launch(void* const* d_in, const int* in_sizes, int n_in,
                              void* d_out, int out_size, void* d_ws, size_t ws_size,
                              hipStream_t stream) {
    const float* x    = (const float*)d_in[0];
    const float* W1   = (const float*)d_in[1];
    const float* W2   = (const float*)d_in[2];
    const int*   erow = (const int*)d_in[3];
    const int*   ecol = (const int*)d_in[4];
    const int N = in_sizes[0] / DIN;
    const int E = in_sizes[3];

    const int nb  = (N + (1 << BSH) - 1) >> BSH;   // 391 buckets (BSH=8)
    const int nch = (E + CHUNK - 1) / CHUNK;       // 782 chunks (CHUNK=2048)

    size_t o = 0;
    auto take = [&](size_t nbytes) {
        void* p = (char*)d_ws + o;
        o += (nbytes + 255) & ~(size_t)255;
        return p;
    };
    int*            HT     = (int*)take((size_t)nb * nch * 4);
    int*            bsum   = (int*)take((size_t)nb * 4);
    int*            bbase  = (int*)take((size_t)(nb + 1) * 4);
    int*            packed = (int*)take((size_t)E * 4);
    int*            csr    = (int*)take((size_t)E * 4);
    int*            offs   = (int*)take((size_t)N * 4);
    int*            degc   = (int*)take((size_t)N * 4);
    float*          invdeg = (float*)take((size_t)N * 4);
    unsigned short* Wt1    = (unsigned short*)take(128 * 128 * 2);
    unsigned short* Wt2    = (unsigned short*)take(64 * 128 * 2);
    unsigned short* h1h    = (unsigned short*)take((size_t)N * DH * 2);  // fp16
    unsigned*       h      = (unsigned*)take((size_t)N * DH * 2);        // fp16
    unsigned short* h2h    = h1h;   // reuse (dead after agg1); 12.8MB needed

    k_prep      <<<96,  256, 0, stream>>>(W1, W2, Wt1, Wt2);
    k_hist      <<<nch, 256, 0, stream>>>(erow, HT, E, nb, nch);
    k_hscan_row <<<nb,  256, 0, stream>>>(HT, bsum, nch);
    k_hscan_base<<<1,   512, 0, stream>>>(bsum, bbase, nb, E);
    k_part      <<<nch, 256, 0, stream>>>(erow, ecol, HT, bbase, packed, E, nb, nch);
    k_build     <<<nb,  256, 0, stream>>>(packed, bbase, csr, offs, degc, invdeg, N, nb);
    k_gemm1<<<(N + 63) / 64, 256, 0, stream>>>(x, Wt1, h1h, N);
    k_agg1 <<<(N + 3) / 4, 256, 0, stream>>>((const uint4*)h1h, offs, degc, invdeg,
                                             csr, (uint4*)h, N);
    k_gemm2<<<(N + 63) / 64, 256, 0, stream>>>(h, Wt2, h2h, N);
    k_agg2 <<<(N + 3) / 4, 256, 0, stream>>>((const uint4*)h2h, offs, degc,
                                             invdeg, csr, (float*)d_out, N);
}

// Round 13
// 264.810 us; speedup vs baseline: 1.5178x; 1.0152x over previous
//
#include <hip/hip_runtime.h>
#include <hip/hip_fp16.h>

// GraphSAGE 2-layer: logits = meanAgg(relu(meanAgg(x@W1)) @ W2)
// N=100000, E=1600000, D_IN=128, D_H=128, D_OUT=64, fp32 in/out.
//
// R9: MFMA gemms. R10: dwordx4 gathers. R12: wave-uniform shfl.
// R13: flat gather tiers. R14/R17: fp8 agg1 slower (VALU / bpermute cost).
// R15: fp16 + packed v_pk_add_f16 agg: agg1 56us, absmax 0.0039.
// R18: counting-sort chain, 265us BEST. R19: atomic fill FAILED (cross-XCD
//      sub-line writes, WRITE 103MB) — but it CALIBRATES the chain:
//      total_R19-total_R18 = 137us ~= R19's chain cost => R18 chain ~free.
//      Hence ~200us hides in gemm1+agg2+gemm2, each <=56us (top-5 all agg1).
// R21: gemm epilogues were 2B-scattered stores (32/thread gemm1, 16 gemm2;
//      19M sub-dword VMEM stores). Replace with LDS-staged coalesced
//      epilogue: barrier -> dense fp16 tile in dead xs[] -> barrier ->
//      flat uint4 copy-out (fully coalesced, 8x fewer store instrs).
// R22: resubmit of R21 (container infra failed twice; no signal).

#define DIN 128
#define DH 128
#define DOUT 64

#define BSH 8                    // 256 rows per bucket
#define COLB 17                  // col fits 17 bits (N=100000 < 2^17)
#define COLM ((1 << COLB) - 1)
#define LRM ((1 << BSH) - 1)
#define CHUNK 2048               // edges per hist/part block
#define CH_PT 8                  // edges per thread

typedef __attribute__((ext_vector_type(8))) short short8;
typedef __attribute__((ext_vector_type(8))) _Float16 half8;
typedef __attribute__((ext_vector_type(4))) float floatx4;

__device__ __forceinline__ unsigned bfpack(float a, float b) {
    unsigned ua = __float_as_uint(a);
    unsigned ub = __float_as_uint(b);
    ua += 0x7fffu + ((ua >> 16) & 1u);
    ub += 0x7fffu + ((ub >> 16) & 1u);
    return (ua >> 16) | (ub & 0xffff0000u);
}
__device__ __forceinline__ unsigned short bf1(float a) {
    unsigned u = __float_as_uint(a);
    u += 0x7fffu + ((u >> 16) & 1u);
    return (unsigned short)(u >> 16);
}

// packed-fp16 accumulate: one uint4 = 8 fp16, 4 v_pk_add_f16
__device__ __forceinline__ void acch2(__half2* a, uint4 v) {
    a[0] = __hadd2(a[0], *(const __half2*)&v.x);
    a[1] = __hadd2(a[1], *(const __half2*)&v.y);
    a[2] = __hadd2(a[2], *(const __half2*)&v.z);
    a[3] = __hadd2(a[3], *(const __half2*)&v.w);
}
__device__ __forceinline__ __half2 h2shfl_xor(__half2 v, int m) {
    int u = __shfl_xor(*(int*)&v, m);
    return *(__half2*)&u;
}
__device__ __forceinline__ unsigned h2bits(__half2 v) {
    return *(unsigned*)&v;
}
__device__ __forceinline__ __half2 h2zero() {
    unsigned z = 0u;
    return *(__half2*)&z;
}

// ---------------- weight prep: fp32 [k][n] -> bf16/fp16 [n][k] ----------
__global__ __launch_bounds__(256) void k_prep(const float* __restrict__ W1,
                                              const float* __restrict__ W2,
                                              unsigned short* __restrict__ Wt1,
                                              unsigned short* __restrict__ Wt2) {
    int idx = blockIdx.x * 256 + threadIdx.x;
    if (idx < 128 * 128) {
        int k = idx >> 7, nn = idx & 127;
        Wt1[nn * 128 + k] = bf1(W1[idx]);          // bf16 for gemm1
    }
    int i2 = idx - 128 * 128;
    if (i2 >= 0 && i2 < 128 * 64) {
        int k = i2 >> 6, nn = i2 & 63;
        Wt2[nn * 128 + k] = __half_as_ushort(__float2half(W2[i2]));  // fp16
    }
}

// ---------------- CSR build (counting sort) ----------------

__global__ __launch_bounds__(256) void k_hist(const int* __restrict__ row,
                                              int* __restrict__ HT,
                                              int E, int nb, int nch) {
    __shared__ int h[512];
    int t = threadIdx.x, c = blockIdx.x;
    for (int i = t; i < nb; i += 256) h[i] = 0;
    __syncthreads();
    int base = c * CHUNK;
#pragma unroll
    for (int i = 0; i < CH_PT; ++i) {
        int e = base + i * 256 + t;
        if (e < E) atomicAdd(&h[row[e] >> BSH], 1);
    }
    __syncthreads();
    for (int i = t; i < nb; i += 256) HT[(size_t)i * nch + c] = h[i];
}

__global__ __launch_bounds__(256) void k_hscan_row(int* __restrict__ HT,
                                                   int* __restrict__ bsum,
                                                   int nch) {
    __shared__ int sh[256];
    int b = blockIdx.x, t = threadIdx.x;
    int carry = 0;
    for (int tile = 0; tile < nch; tile += 256) {
        int idx = tile + t;
        int v = (idx < nch) ? HT[(size_t)b * nch + idx] : 0;
        sh[t] = v;
        __syncthreads();
        for (int d = 1; d < 256; d <<= 1) {
            int u = (t >= d) ? sh[t - d] : 0;
            __syncthreads();
            sh[t] += u;
            __syncthreads();
        }
        if (idx < nch) HT[(size_t)b * nch + idx] = carry + sh[t] - v;
        carry += sh[255];
        __syncthreads();
    }
    if (t == 0) bsum[b] = carry;
}

// 512-thread scan (nb up to 512 buckets with BSH=8)
__global__ __launch_bounds__(512) void k_hscan_base(const int* __restrict__ bsum,
                                                    int* __restrict__ bucketBase,
                                                    int nb, int E) {
    __shared__ int sh[512];
    int t = threadIdx.x;
    int v = (t < nb) ? bsum[t] : 0;
    sh[t] = v;
    __syncthreads();
    for (int d = 1; d < 512; d <<= 1) {
        int u = (t >= d) ? sh[t - d] : 0;
        __syncthreads();
        sh[t] += u;
        __syncthreads();
    }
    if (t < nb) bucketBase[t] = sh[t] - v;
    if (t == 0) bucketBase[nb] = E;
}

__global__ __launch_bounds__(256) void k_part(const int* __restrict__ row,
                                              const int* __restrict__ col,
                                              const int* __restrict__ HT,
                                              const int* __restrict__ bucketBase,
                                              int* __restrict__ packed,
                                              int E, int nb, int nch) {
    __shared__ int cur[512];
    int t = threadIdx.x, c = blockIdx.x;
    for (int i = t; i < nb; i += 256)
        cur[i] = HT[(size_t)i * nch + c] + bucketBase[i];
    __syncthreads();
    int base = c * CHUNK;
#pragma unroll
    for (int i = 0; i < CH_PT; ++i) {
        int e = base + i * 256 + t;
        if (e < E) {
            int r = row[e], cc = col[e];
            int b = r >> BSH;
            int pos = atomicAdd(&cur[b], 1);
            packed[pos] = ((r & LRM) << COLB) | cc;
        }
    }
}

__global__ __launch_bounds__(256) void k_build(const int* __restrict__ packed,
                                               const int* __restrict__ bucketBase,
                                               int* __restrict__ csr,
                                               int* __restrict__ offs,
                                               int* __restrict__ degc,
                                               float* __restrict__ invdeg,
                                               int N, int nb) {
    __shared__ int hist[256], scn[256], part[256];
    int t = threadIdx.x, b = blockIdx.x;
    int lo = bucketBase[b], hi = bucketBase[b + 1];
    int base_row = b << BSH;
    int nloc = N - base_row; if (nloc > 256) nloc = 256;
    hist[t] = 0;
    __syncthreads();
    for (int e = lo + t; e < hi; e += 256)
        atomicAdd(&hist[packed[e] >> COLB], 1);
    __syncthreads();
    int a = hist[t];
    part[t] = a;
    __syncthreads();
    for (int d = 1; d < 256; d <<= 1) {
        int v = (t >= d) ? part[t - d] : 0;
        __syncthreads();
        part[t] += v;
        __syncthreads();
    }
    scn[t] = part[t] - a;              // exclusive scan
    __syncthreads();
    for (int i = t; i < nloc; i += 256) {
        int r = base_row + i;
        offs[r] = lo + scn[i];
        int d = hist[i];
        degc[r] = d;
        invdeg[r] = 1.0f / (float)d;
    }
    __syncthreads();
    for (int e = lo + t; e < hi; e += 256) {
        int p = packed[e];
        int pos = lo + atomicAdd(&scn[p >> COLB], 1);
        csr[pos] = p & COLM;
    }
}

// ---------------- MFMA GEMMs ----------------

// h1h[n,128](fp16) = X @ W1 (bf16 MFMA, fp16 store). 64-row block.
// R21: LDS-staged coalesced epilogue (old: 32 scattered 2B stores/thread).
__global__ __launch_bounds__(256) void k_gemm1(const float* __restrict__ X,
                                               const unsigned short* __restrict__ Wt,
                                               unsigned short* __restrict__ H1h, int n) {
    __shared__ unsigned short xs[64][136];    // pitch 272B: 2-way-bank-safe b128
    __shared__ unsigned short wt[128][136];
    int tid = threadIdx.x;
    int r0 = blockIdx.x * 64;

    for (int i = tid; i < 64 * 32; i += 256) {
        int r = i >> 5, c4 = i & 31;
        float4 v = make_float4(0.f, 0.f, 0.f, 0.f);
        if (r0 + r < n) v = ((const float4*)X)[(size_t)(r0 + r) * 32 + c4];
        *(uint2*)&xs[r][c4 * 4] = make_uint2(bfpack(v.x, v.y), bfpack(v.z, v.w));
    }
    for (int i = tid; i < 128 * 16; i += 256) {
        int r = i >> 4, c = i & 15;
        *(uint4*)&wt[r][c * 8] = ((const uint4*)Wt)[r * 16 + c];
    }
    __syncthreads();

    int w = tid >> 6, lane = tid & 63;
    int ml = lane & 15, q = lane >> 4;
    floatx4 acc[8];
#pragma unroll
    for (int t = 0; t < 8; ++t) acc[t] = (floatx4)(0.f);

#pragma unroll
    for (int kc = 0; kc < 4; ++kc) {
        short8 af = *(const short8*)&xs[w * 16 + ml][kc * 32 + q * 8];
#pragma unroll
        for (int nt = 0; nt < 8; ++nt) {
            short8 bf = *(const short8*)&wt[nt * 16 + ml][kc * 32 + q * 8];
            acc[nt] = __builtin_amdgcn_mfma_f32_16x16x32_bf16(af, bf, acc[nt], 0, 0, 0);
        }
    }

    // epilogue: all waves done reading xs before dense overwrite
    __syncthreads();
    unsigned short* xsf = (unsigned short*)&xs[0][0];   // dense [64][128] halves
#pragma unroll
    for (int nt = 0; nt < 8; ++nt)
#pragma unroll
        for (int r = 0; r < 4; ++r)
            xsf[(w * 16 + q * 4 + r) * 128 + nt * 16 + ml] =
                __half_as_ushort(__float2half(acc[nt][r]));
    __syncthreads();
    int rows = n - r0; if (rows > 64) rows = 64;
    uint4* dst = (uint4*)(H1h + (size_t)r0 * 128);
    const uint4* src = (const uint4*)xsf;
    for (int i = tid; i < rows * 16; i += 256) dst[i] = src[i];
}

// h2h[n,64](fp16) = h(fp16) @ W2 (f16 MFMA). Same structure, N=64.
// R21: LDS-staged coalesced epilogue.
__global__ __launch_bounds__(256) void k_gemm2(const unsigned* __restrict__ Hin,
                                               const unsigned short* __restrict__ Wt,
                                               unsigned short* __restrict__ H2h, int n) {
    __shared__ unsigned short xs[64][136];
    __shared__ unsigned short wt[64][136];
    int tid = threadIdx.x;
    int r0 = blockIdx.x * 64;

    for (int i = tid; i < 64 * 16; i += 256) {
        int r = i >> 4, c = i & 15;
        uint4 v = make_uint4(0u, 0u, 0u, 0u);
        if (r0 + r < n) v = ((const uint4*)Hin)[(size_t)(r0 + r) * 16 + c];
        *(uint4*)&xs[r][c * 8] = v;
    }
    for (int i = tid; i < 64 * 16; i += 256) {
        int r = i >> 4, c = i & 15;
        *(uint4*)&wt[r][c * 8] = ((const uint4*)Wt)[r * 16 + c];
    }
    __syncthreads();

    int w = tid >> 6, lane = tid & 63;
    int ml = lane & 15, q = lane >> 4;
    floatx4 acc[4];
#pragma unroll
    for (int t = 0; t < 4; ++t) acc[t] = (floatx4)(0.f);

#pragma unroll
    for (int kc = 0; kc < 4; ++kc) {
        half8 af = *(const half8*)&xs[w * 16 + ml][kc * 32 + q * 8];
#pragma unroll
        for (int nt = 0; nt < 4; ++nt) {
            half8 bf = *(const half8*)&wt[nt * 16 + ml][kc * 32 + q * 8];
            acc[nt] = __builtin_amdgcn_mfma_f32_16x16x32_f16(af, bf, acc[nt], 0, 0, 0);
        }
    }

    __syncthreads();
    unsigned short* xsf = (unsigned short*)&xs[0][0];   // dense [64][64] halves
#pragma unroll
    for (int nt = 0; nt < 4; ++nt)
#pragma unroll
        for (int r = 0; r < 4; ++r)
            xsf[(w * 16 + q * 4 + r) * 64 + nt * 16 + ml] =
                __half_as_ushort(__float2half(acc[nt][r]));
    __syncthreads();
    int rows = n - r0; if (rows > 64) rows = 64;
    uint4* dst = (uint4*)(H2h + (size_t)r0 * 64);
    const uint4* src = (const uint4*)xsf;
    for (int i = tid; i < rows * 8; i += 256) dst[i] = src[i];
}

// ---------------- Aggregations (R15 structure) ----------------

// agg1: h[row](fp16) = relu((1/deg) * sum h1h[c]), D=128 (row = 16 uint4).
#define A1_SLOT(vv, s)                                                      \
    {                                                                       \
        int j = (s) * 4 + g;                                                \
        int c = __shfl(idx, (j < nd) ? j : 0);                              \
        vv = make_uint4(0u, 0u, 0u, 0u);                                    \
        if (j < nd) vv = H1h[((unsigned)c << 4) + sl];                      \
    }

__global__ __launch_bounds__(256) void k_agg1(const uint4* __restrict__ H1h,
                                              const int* __restrict__ offs,
                                              const int* __restrict__ degc,
                                              const float* __restrict__ invdeg,
                                              const int* __restrict__ csr,
                                              uint4* __restrict__ Hout, int n) {
    int wave = threadIdx.x >> 6, lane = threadIdx.x & 63;
    int row = blockIdx.x * 4 + wave;
    if (row >= n) return;
    int start = offs[row], d = degc[row];
    float inv = invdeg[row];
    int g = lane >> 4;       // neighbor slot 0..3
    int sl = lane & 15;      // 16B segment within 256B fp16 row

    int nd = d < 64 ? d : 64;
    int idx = (lane < nd) ? csr[start + lane] : 0;

    __half2 acc[4];
#pragma unroll
    for (int k = 0; k < 4; ++k) acc[k] = h2zero();

    uint4 v0, v1, v2, v3;
    A1_SLOT(v0, 0) A1_SLOT(v1, 1) A1_SLOT(v2, 2) A1_SLOT(v3, 3)
    acch2(acc, v0); acch2(acc, v1); acch2(acc, v2); acch2(acc, v3);
    if (nd > 16) {
        A1_SLOT(v0, 4) A1_SLOT(v1, 5) A1_SLOT(v2, 6) A1_SLOT(v3, 7)
        acch2(acc, v0); acch2(acc, v1); acch2(acc, v2); acch2(acc, v3);
    }
    if (nd > 32) {
        A1_SLOT(v0, 8) A1_SLOT(v1, 9) A1_SLOT(v2, 10) A1_SLOT(v3, 11)
        acch2(acc, v0); acch2(acc, v1); acch2(acc, v2); acch2(acc, v3);
    }
    if (nd > 48) {
        A1_SLOT(v0, 12) A1_SLOT(v1, 13) A1_SLOT(v2, 14) A1_SLOT(v3, 15)
        acch2(acc, v0); acch2(acc, v1); acch2(acc, v2); acch2(acc, v3);
    }
    if (d > 64) {                    // rare fallback
        for (int i = 64; i < d; i += 4) {
            int j = i + g;
            uint4 v = make_uint4(0u, 0u, 0u, 0u);
            if (j < d) {
                int c = csr[start + j];
                v = H1h[((unsigned)c << 4) + sl];
            }
            acch2(acc, v);
        }
    }

#pragma unroll
    for (int k = 0; k < 4; ++k) {
        acc[k] = __hadd2(acc[k], h2shfl_xor(acc[k], 16));
        acc[k] = __hadd2(acc[k], h2shfl_xor(acc[k], 32));
    }

    if (g == 0) {
        float f[8];
#pragma unroll
        for (int k = 0; k < 4; ++k) {
            f[2 * k]     = fmaxf(__low2float(acc[k]) * inv, 0.f);
            f[2 * k + 1] = fmaxf(__high2float(acc[k]) * inv, 0.f);
        }
        uint4 o;
        __half2 t0 = __floats2half2_rn(f[0], f[1]);
        __half2 t1 = __floats2half2_rn(f[2], f[3]);
        __half2 t2 = __floats2half2_rn(f[4], f[5]);
        __half2 t3 = __floats2half2_rn(f[6], f[7]);
        o.x = h2bits(t0); o.y = h2bits(t1); o.z = h2bits(t2); o.w = h2bits(t3);
        Hout[(size_t)row * 16 + sl] = o;
    }
}

// agg2: Out[row](fp32) = (1/deg) * sum h2h[c], D=64 (row = 8 uint4, fp16).
#define A2_SLOT(vv, s)                                                      \
    {                                                                       \
        int j = (s) * 8 + g;                                                \
        int c = __shfl(idx, (j < nd) ? j : 0);                              \
        vv = make_uint4(0u, 0u, 0u, 0u);                                    \
        if (j < nd) vv = H2h[((unsigned)c << 3) + sl];                      \
    }

__global__ __launch_bounds__(256) void k_agg2(const uint4* __restrict__ H2h,
                                              const int* __restrict__ offs,
                                              const int* __restrict__ degc,
                                              const float* __restrict__ invdeg,
                                              const int* __restrict__ csr,
                                              float* __restrict__ Out, int n) {
    int wave = threadIdx.x >> 6, lane = threadIdx.x & 63;
    int row = blockIdx.x * 4 + wave;
    if (row >= n) return;
    int start = offs[row], d = degc[row];
    float inv = invdeg[row];
    int g = lane >> 3;       // neighbor slot 0..7
    int sl = lane & 7;       // 16B segment within 128B fp16 row

    int nd = d < 64 ? d : 64;
    int idx = (lane < nd) ? csr[start + lane] : 0;

    __half2 acc[4];
#pragma unroll
    for (int k = 0; k < 4; ++k) acc[k] = h2zero();

    uint4 v0, v1;
    A2_SLOT(v0, 0) A2_SLOT(v1, 1)
    acch2(acc, v0); acch2(acc, v1);
    if (nd > 16) {
        A2_SLOT(v0, 2) A2_SLOT(v1, 3)
        acch2(acc, v0); acch2(acc, v1);
    }
    if (nd > 32) {
        A2_SLOT(v0, 4) A2_SLOT(v1, 5)
        acch2(acc, v0); acch2(acc, v1);
    }
    if (nd > 48) {
        A2_SLOT(v0, 6) A2_SLOT(v1, 7)
        acch2(acc, v0); acch2(acc, v1);
    }
    if (d > 64) {                    // rare fallback
        for (int i = 64; i < d; i += 8) {
            int j = i + g;
            uint4 v = make_uint4(0u, 0u, 0u, 0u);
            if (j < d) {
                int c = csr[start + j];
                v = H2h[((unsigned)c << 3) + sl];
            }
            acch2(acc, v);
        }
    }

#pragma unroll
    for (int k = 0; k < 4; ++k) {
        acc[k] = __hadd2(acc[k], h2shfl_xor(acc[k], 8));
        acc[k] = __hadd2(acc[k], h2shfl_xor(acc[k], 16));
        acc[k] = __hadd2(acc[k], h2shfl_xor(acc[k], 32));
    }

    if (g == 0) {
        float4 o0, o1;
        o0.x = __low2float(acc[0]) * inv;  o0.y = __high2float(acc[0]) * inv;
        o0.z = __low2float(acc[1]) * inv;  o0.w = __high2float(acc[1]) * inv;
        o1.x = __low2float(acc[2]) * inv;  o1.y = __high2float(acc[2]) * inv;
        o1.z = __low2float(acc[3]) * inv;  o1.w = __high2float(acc[3]) * inv;
        ((float4*)Out)[(size_t)row * 16 + sl * 2]     = o0;
        ((float4*)Out)[(size_t)row * 16 + sl * 2 + 1] = o1;
    }
}

extern "C" void kernel_launch(void* const* d_in, const int* in_sizes, int n_in,
                              void* d_out, int out_size, void* d_ws, size_t ws_size,
                              hipStream_t stream) {
    const float* x    = (const float*)d_in[0];
    const float* W1   = (const float*)d_in[1];
    const float* W2   = (const float*)d_in[2];
    const int*   erow = (const int*)d_in[3];
    const int*   ecol = (const int*)d_in[4];
    const int N = in_sizes[0] / DIN;
    const int E = in_sizes[3];

    const int nb  = (N + (1 << BSH) - 1) >> BSH;   // 391 buckets (BSH=8)
    const int nch = (E + CHUNK - 1) / CHUNK;       // 782 chunks (CHUNK=2048)

    size_t o = 0;
    auto take = [&](size_t nbytes) {
        void* p = (char*)d_ws + o;
        o += (nbytes + 255) & ~(size_t)255;
        return p;
    };
    int*            HT     = (int*)take((size_t)nb * nch * 4);
    int*            bsum   = (int*)take((size_t)nb * 4);
    int*            bbase  = (int*)take((size_t)(nb + 1) * 4);
    int*            packed = (int*)take((size_t)E * 4);
    int*            csr    = (int*)take((size_t)E * 4);
    int*            offs   = (int*)take((size_t)N * 4);
    int*            degc   = (int*)take((size_t)N * 4);
    float*          invdeg = (float*)take((size_t)N * 4);
    unsigned short* Wt1    = (unsigned short*)take(128 * 128 * 2);
    unsigned short* Wt2    = (unsigned short*)take(64 * 128 * 2);
    unsigned short* h1h    = (unsigned short*)take((size_t)N * DH * 2);  // fp16
    unsigned*       h      = (unsigned*)take((size_t)N * DH * 2);        // fp16
    unsigned short* h2h    = h1h;   // reuse (dead after agg1); 12.8MB needed

    k_prep      <<<96,  256, 0, stream>>>(W1, W2, Wt1, Wt2);
    k_hist      <<<nch, 256, 0, stream>>>(erow, HT, E, nb, nch);
    k_hscan_row <<<nb,  256, 0, stream>>>(HT, bsum, nch);
    k_hscan_base<<<1,   512, 0, stream>>>(bsum, bbase, nb, E);
    k_part      <<<nch, 256, 0, stream>>>(erow, ecol, HT, bbase, packed, E, nb, nch);
    k_build     <<<nb,  256, 0, stream>>>(packed, bbase, csr, offs, degc, invdeg, N, nb);
    k_gemm1<<<(N + 63) / 64, 256, 0, stream>>>(x, Wt1, h1h, N);
    k_agg1 <<<(N + 3) / 4, 256, 0, stream>>>((const uint4*)h1h, offs, degc, invdeg,
                                             csr, (uint4*)h, N);
    k_gemm2<<<(N + 63) / 64, 256, 0, stream>>>(h, Wt2, h2h, N);
    k_agg2 <<<(N + 3) / 4, 256, 0, stream>>>((const uint4*)h2h, offs, degc,
                                             invdeg, csr, (float*)d_out, N);
}